// Round 4
// baseline (2726.956 us; speedup 1.0000x reference)
//
#include <hip/hip_runtime.h>
#include <hip/hip_bf16.h>

#define N_  50000
#define R_  1000
#define A_  5000
#define D_  256
#define H_  4
#define DH_ 64
#define E_  200000
#define ER_ 150000
#define EA_ 150000
#define TNB 32   // nodes per transform block

// ---------- monotone float<->uint key for atomicMax on floats ----------
__device__ __forceinline__ unsigned f2key(float f) {
    unsigned b = __float_as_uint(f);
    return (b & 0x80000000u) ? ~b : (b | 0x80000000u);
}
__device__ __forceinline__ float key2f(unsigned k) {
    unsigned b = (k & 0x80000000u) ? (k ^ 0x80000000u) : ~k;
    return __uint_as_float(b);
}

// ---------- concept: atomic mean-aggregate (float4 per thread) ----------
__global__ void k_concept_accum(const int* __restrict__ idx, const float* __restrict__ emb,
                                float* __restrict__ sum, int* __restrict__ deg, int nE) {
    int gid = blockIdx.x * blockDim.x + threadIdx.x;
    if (gid >= nE * 16) return;
    int e = gid >> 4, q = gid & 15;
    int row = idx[2 * e], col = idx[2 * e + 1];
    float4 v = *(const float4*)(emb + (size_t)col * 64 + q * 4);
    float* dst = sum + (size_t)row * 64 + q * 4;
    atomicAdd(dst + 0, v.x);
    atomicAdd(dst + 1, v.y);
    atomicAdd(dst + 2, v.z);
    atomicAdd(dst + 3, v.w);
    if (q == 0) atomicAdd(&deg[row], 1);
}

__global__ void k_concept_final(const float* __restrict__ sum_rel, const int* __restrict__ deg_rel,
                                const float* __restrict__ sum_attr, const int* __restrict__ deg_attr,
                                float* __restrict__ out) {
    int gid = blockIdx.x * blockDim.x + threadIdx.x;
    if (gid >= N_ * 32) return;
    int n = gid >> 5, q = gid & 31;
    int d0 = q * 4;
    float4 v;
    float inv;
    if (d0 < 64) {
        int dg = deg_rel[n];
        inv = dg > 0 ? 1.f / (float)dg : 0.f;
        v = *(const float4*)(sum_rel + (size_t)n * 64 + d0);
    } else {
        int dg = deg_attr[n];
        inv = dg > 0 ? 1.f / (float)dg : 0.f;
        v = *(const float4*)(sum_attr + (size_t)n * 64 + (d0 - 64));
    }
    v.x = fmaxf(v.x * inv, 0.f);
    v.y = fmaxf(v.y * inv, 0.f);
    v.z = fmaxf(v.z * inv, 0.f);
    v.w = fmaxf(v.w * inv, 0.f);
    *(float4*)(out + (size_t)n * 640 + 512 + d0) = v;
    *(float4*)(out + (size_t)N_ * 640 + (size_t)n * 128 + d0) = v;
}

// ---------- h0 stage ----------
__global__ void k_h0_denom(const int* __restrict__ eidx, const float* __restrict__ eval,
                           float* __restrict__ z0) {
    int e = blockIdx.x * blockDim.x + threadIdx.x;
    if (e >= E_) return;
    atomicAdd(&z0[eidx[2 * e]], expf(eval[e]));
}

__global__ void k_h0_scatter(const int* __restrict__ eidx, const float* __restrict__ eval,
                             const float* __restrict__ z0, const float* __restrict__ ent_emb,
                             float* __restrict__ h0) {
    int gid = blockIdx.x * blockDim.x + threadIdx.x;
    if (gid >= E_ * 64) return;
    int e = gid >> 6, q = gid & 63;
    int row = eidx[2 * e], col = eidx[2 * e + 1];
    float w = expf(eval[e]) / z0[row];
    float4 v = *(const float4*)(ent_emb + (size_t)col * 256 + q * 4);
    float* dst = h0 + (size_t)row * 256 + q * 4;
    atomicAdd(dst + 0, w * v.x);
    atomicAdd(dst + 1, w * v.y);
    atomicAdd(dst + 2, w * v.z);
    atomicAdd(dst + 3, w * v.w);
}

// ---------- per-node transform: register-blocked, LDS-staged ----------
__global__ void __launch_bounds__(256) k_transform(
        const float* __restrict__ h, const float* __restrict__ Wk,
        const float* __restrict__ ak, float* __restrict__ s1, float* __restrict__ s2) {
    __shared__ float hs[TNB * 256];            // 32 KB
    int tid = threadIdx.x;
    int lane = tid & 63;
    int head = tid >> 6;                       // wave per head
    int nbase = blockIdx.x * TNB;
    int nnodes = min(TNB, N_ - nbase);

    // W column (this head, this lane) into registers — reused for all TNB nodes
    float Wreg[64];
    const float* W = Wk + head * 4096;
    #pragma unroll
    for (int d = 0; d < 64; ++d) Wreg[d] = W[d * 64 + lane];

    // stage relu(h) tile, float4-vectorized
    const float4* src = (const float4*)(h + (size_t)nbase * 256);
    for (int i = tid; i < nnodes * 64; i += 256) {
        float4 v = src[i];
        v.x = fmaxf(v.x, 0.f);
        v.y = fmaxf(v.y, 0.f);
        v.z = fmaxf(v.z, 0.f);
        v.w = fmaxf(v.w, 0.f);
        ((float4*)hs)[i] = v;
    }
    __syncthreads();

    const float* akh = ak + head * 128;
    float a1 = akh[lane], a2 = akh[64 + lane];

    for (int n = 0; n < nnodes; ++n) {
        const float* hr = hs + n * 256 + head * 64;
        float t0 = 0.f, t1 = 0.f;              // dual accumulators break dep chain
        #pragma unroll
        for (int d = 0; d < 64; d += 8) {
            float4 u = *(const float4*)(hr + d);      // LDS broadcast
            float4 v = *(const float4*)(hr + d + 4);
            t0 = fmaf(u.x, Wreg[d + 0], t0);
            t1 = fmaf(u.y, Wreg[d + 1], t1);
            t0 = fmaf(u.z, Wreg[d + 2], t0);
            t1 = fmaf(u.w, Wreg[d + 3], t1);
            t0 = fmaf(v.x, Wreg[d + 4], t0);
            t1 = fmaf(v.y, Wreg[d + 5], t1);
            t0 = fmaf(v.z, Wreg[d + 6], t0);
            t1 = fmaf(v.w, Wreg[d + 7], t1);
        }
        float t = fmaxf(t0 + t1, 0.f);         // relu(W h)
        float p1 = t * a1, p2 = t * a2;
        #pragma unroll
        for (int s = 32; s >= 1; s >>= 1) {
            p1 += __shfl_xor(p1, s, 64);
            p2 += __shfl_xor(p2, s, 64);
        }
        if (lane == 0) {
            s1[(nbase + n) * 4 + head] = p1;
            s2[(nbase + n) * 4 + head] = p2;
        }
    }
}

// ---------- attention pass 1: score + leaky-relu + global max per head ----------
__global__ void k_attn1(const int* __restrict__ eidx,
                        const float* __restrict__ s1, const float* __restrict__ s2,
                        float* __restrict__ a_arr, unsigned* __restrict__ Mkey) {
    __shared__ unsigned smax[4];
    int tid = threadIdx.x;
    if (tid < 4) smax[tid] = 0u;
    __syncthreads();
    int gid = blockIdx.x * blockDim.x + tid;
    if (gid < E_ * 4) {
        int e = gid >> 2, hh = gid & 3;
        float a = s1[eidx[2 * e] * 4 + hh] + s2[eidx[2 * e + 1] * 4 + hh];
        a = (a > 0.f) ? a : 0.3f * a;          // leaky_relu(0.3)
        a_arr[gid] = a;
        atomicMax(&smax[hh], f2key(a));
    }
    __syncthreads();
    if (tid < 4 && smax[tid]) atomicMax(&Mkey[tid], smax[tid]);
}

// ---------- attention pass 2: sum of exp ----------
__global__ void k_attn2(float* __restrict__ a_arr, const unsigned* __restrict__ Mkey,
                        float* __restrict__ S) {
    __shared__ float ssum[4];
    int tid = threadIdx.x;
    if (tid < 4) ssum[tid] = 0.f;
    __syncthreads();
    int gid = blockIdx.x * blockDim.x + tid;
    if (gid < E_ * 4) {
        int hh = gid & 3;
        float v = expf(a_arr[gid] - key2f(Mkey[hh]));
        a_arr[gid] = v;
        atomicAdd(&ssum[hh], v);
    }
    __syncthreads();
    if (tid < 4 && ssum[tid] != 0.f) atomicAdd(&S[tid], ssum[tid]);
}

// ---------- attention pass 3: normalize -> exp -> per-row sums ----------
__global__ void k_attn3(const int* __restrict__ eidx, float* __restrict__ a_arr,
                        const float* __restrict__ S, float* __restrict__ zl) {
    int gid = blockIdx.x * blockDim.x + threadIdx.x;
    if (gid >= E_ * 4) return;
    int e = gid >> 2, hh = gid & 3;
    float v = a_arr[gid] / S[hh];              // global softmax value
    float ev = expf(v);                        // seg-softmax numerator
    a_arr[gid] = ev;
    atomicAdd(&zl[eidx[2 * e] * 4 + hh], ev);
}

// ---------- aggregation scatter (float4 per thread) ----------
__global__ void k_aggr_scatter(const int* __restrict__ eidx, const float* __restrict__ a_arr,
                               const float* __restrict__ zl, const float* __restrict__ h_in,
                               float* __restrict__ acc) {
    int gid = blockIdx.x * blockDim.x + threadIdx.x;
    if (gid >= E_ * 64) return;
    int e = gid >> 6, q = gid & 63;
    int head = q >> 4;
    int row = eidx[2 * e], col = eidx[2 * e + 1];
    float w = a_arr[e * 4 + head] / zl[row * 4 + head];
    float4 v = *(const float4*)(h_in + (size_t)col * 256 + q * 4);
    float* dst = acc + (size_t)row * 256 + q * 4;
    atomicAdd(dst + 0, w * fmaxf(v.x, 0.f));
    atomicAdd(dst + 1, w * fmaxf(v.y, 0.f));
    atomicAdd(dst + 2, w * fmaxf(v.z, 0.f));
    atomicAdd(dst + 3, w * fmaxf(v.w, 0.f));
}

// ---------- finalize: tanh -> out + next-layer h ----------
__global__ void k_finalize(float* __restrict__ acc, float* __restrict__ out, int layer) {
    int gid = blockIdx.x * blockDim.x + threadIdx.x;
    if (gid >= N_ * 64) return;
    int n = gid >> 6, q = gid & 63;
    float4 v = ((const float4*)acc)[gid];
    v.x = tanhf(v.x);
    v.y = tanhf(v.y);
    v.z = tanhf(v.z);
    v.w = tanhf(v.w);
    ((float4*)acc)[gid] = v;                   // h for next layer
    *(float4*)(out + (size_t)n * 640 + layer * 256 + q * 4) = v;
}

// ---------- host ----------
static inline size_t align256(size_t x) { return (x + 255) & ~(size_t)255; }

extern "C" void kernel_launch(void* const* d_in, const int* in_sizes, int n_in,
                              void* d_out, int out_size, void* d_ws, size_t ws_size,
                              hipStream_t stream) {
    const float* ent_emb     = (const float*)d_in[0];
    const float* rel_emb     = (const float*)d_in[1];
    const float* attr_emb    = (const float*)d_in[2];
    const float* ent_kernels = (const float*)d_in[3];  // (L,H,64,64)
    const float* ent_attn    = (const float*)d_in[4];  // (L,H,128)
    const float* edge_val    = (const float*)d_in[5];
    const int*   edge_index  = (const int*)d_in[6];
    const int*   rel_index   = (const int*)d_in[7];
    const int*   attr_index  = (const int*)d_in[8];
    float* out = (float*)d_out;   // reference output dtype is float32

    char* w = (char*)d_ws;
    size_t off = 0;
    auto carve = [&](size_t bytes) { void* p = w + off; off += align256(bytes); return p; };

    // group A (zeroed once): concept sums/degrees + h0 softmax denom
    size_t gA_beg = off;
    float* sum_rel  = (float*)carve((size_t)N_ * 64 * 4);
    float* sum_attr = (float*)carve((size_t)N_ * 64 * 4);
    int*   deg_rel  = (int*)carve((size_t)N_ * 4);
    int*   deg_attr = (int*)carve((size_t)N_ * 4);
    float* z0       = (float*)carve((size_t)N_ * 4);
    size_t gA_size = off - gA_beg;

    float* s1    = (float*)carve((size_t)N_ * 4 * 4);
    float* s2    = (float*)carve((size_t)N_ * 4 * 4);
    float* a_arr = (float*)carve((size_t)E_ * 4 * 4);

    // group B (zeroed per layer): seg-softmax row sums + global max/denom
    size_t gB_beg = off;
    float*    zl   = (float*)carve((size_t)N_ * 4 * 4);
    unsigned* Mkey = (unsigned*)carve(4 * 4);
    float*    S    = (float*)carve(4 * 4);
    size_t gB_size = off - gB_beg;

    float* h_a = (float*)carve((size_t)N_ * 256 * 4);
    float* h_b = (float*)carve((size_t)N_ * 256 * 4);

    // ---- concept aggregations ----
    hipMemsetAsync(w + gA_beg, 0, gA_size, stream);
    k_concept_accum<<<(ER_ * 16 + 255) / 256, 256, 0, stream>>>(rel_index, rel_emb, sum_rel, deg_rel, ER_);
    k_concept_accum<<<(EA_ * 16 + 255) / 256, 256, 0, stream>>>(attr_index, attr_emb, sum_attr, deg_attr, EA_);
    k_concept_final<<<(N_ * 32 + 255) / 256, 256, 0, stream>>>(sum_rel, deg_rel, sum_attr, deg_attr, out);

    // ---- h0: edge-softmax weighted aggregation of ent_emb ----
    k_h0_denom<<<(E_ + 255) / 256, 256, 0, stream>>>(edge_index, edge_val, z0);
    hipMemsetAsync(h_a, 0, (size_t)N_ * 256 * 4, stream);
    k_h0_scatter<<<(E_ * 64 + 255) / 256, 256, 0, stream>>>(edge_index, edge_val, z0, ent_emb, h_a);

    // ---- 2 GAT layers ----
    for (int l = 0; l < 2; ++l) {
        float* h_in = (l == 0) ? h_a : h_b;
        float* acc  = (l == 0) ? h_b : h_a;
        k_transform<<<(N_ + TNB - 1) / TNB, 256, 0, stream>>>(
            h_in, ent_kernels + (size_t)l * H_ * 64 * 64, ent_attn + (size_t)l * H_ * 128, s1, s2);
        hipMemsetAsync(w + gB_beg, 0, gB_size, stream);
        hipMemsetAsync(acc, 0, (size_t)N_ * 256 * 4, stream);
        k_attn1<<<(E_ * 4 + 255) / 256, 256, 0, stream>>>(edge_index, s1, s2, a_arr, Mkey);
        k_attn2<<<(E_ * 4 + 255) / 256, 256, 0, stream>>>(a_arr, Mkey, S);
        k_attn3<<<(E_ * 4 + 255) / 256, 256, 0, stream>>>(edge_index, a_arr, S, zl);
        k_aggr_scatter<<<(E_ * 64 + 255) / 256, 256, 0, stream>>>(edge_index, a_arr, zl, h_in, acc);
        k_finalize<<<(N_ * 64 + 255) / 256, 256, 0, stream>>>(acc, out, l);
    }
}